// Round 8
// baseline (728.046 us; speedup 1.0000x reference)
//
#include <hip/hip_runtime.h>
#include <hip/hip_bf16.h>

typedef unsigned short u16;
typedef __attribute__((ext_vector_type(8))) short short8;
typedef __attribute__((ext_vector_type(4))) short short4v;
typedef __attribute__((ext_vector_type(4))) float float4v;

__device__ __forceinline__ u16 f2b(float f) {  // RNE f32->bf16 bits (proven)
    unsigned int u = __float_as_uint(f);
    return (u16)((u + 0x7fffu + ((u >> 16) & 1u)) >> 16);
}

#define MFMA(a, b, c) __builtin_amdgcn_mfma_f32_16x16x32_bf16((a), (b), (c), 0, 0, 0)

// ws (u16): wqk[8][128][128] @0 : wqk[h][c][c0] = 0.125 * sum_d Wq[c0][h64+d]*Wk[c][h64+d]
//           wvt[8][64][128] @131072 : Wv_h^T[dv][c]
//           wot[128][512]   @196608 : Wo^T[cout][n]
//           xt[4][128][128][128] @262144 (fast path only): x transposed to [b][y][x][c] bf16
__global__ void prep_weights(const float* __restrict__ Wq,
                             const float* __restrict__ Wkv,
                             const float* __restrict__ Wo,
                             u16* __restrict__ ws)
{
    const int bid = blockIdx.x, tid = threadIdx.x;
    if (bid < 128) {   // wqk: block = (h, 32-row group g, 32-col group c0g)
        __shared__ float wq_s[32 * 65];
        __shared__ float wk_s[32 * 65];
        const int h = bid >> 4, g = (bid >> 2) & 3, c0g = bid & 3;
        for (int i = tid; i < 2048; i += 256) {
            int r = i >> 6, d = i & 63;
            wq_s[r * 65 + d] = Wq[(c0g * 32 + r) * 512 + h * 64 + d];
            wk_s[r * 65 + d] = Wkv[(g * 32 + r) * 1024 + h * 64 + d];
        }
        __syncthreads();
        const int c0l = tid & 31, ccb = (tid >> 5) * 4;
        float acc[4] = {0.f, 0.f, 0.f, 0.f};
        for (int d = 0; d < 64; ++d) {
            float a = wq_s[c0l * 65 + d];
#pragma unroll
            for (int cc = 0; cc < 4; ++cc)
                acc[cc] = fmaf(a, wk_s[(ccb + cc) * 65 + d], acc[cc]);
        }
#pragma unroll
        for (int cc = 0; cc < 4; ++cc)
            ws[h * 16384 + (g * 32 + ccb + cc) * 128 + c0g * 32 + c0l] =
                f2b(0.125f * acc[cc]);
    } else {
        int idx = (bid - 128) * 256 + tid;
        if (idx < 65536) {                 // wvt
            int h = idx >> 13, c = (idx >> 6) & 127, dv = idx & 63;
            ws[131072 + h * 8192 + dv * 128 + c] =
                f2b(Wkv[c * 1024 + 512 + h * 64 + dv]);
        } else {                           // wot
            int j2 = idx - 65536;
            int cout = j2 >> 9, n = j2 & 511;
            ws[196608 + j2] = f2b(Wo[n * 128 + cout]);
        }
    }
}

// x[b][c][y][x] f32 -> xt[b][y][x][c] bf16 (one-time, ~10us)
__global__ void xt_prep(const float* __restrict__ xg, u16* __restrict__ xt)
{
    __shared__ u16 tile[128 * 137];
    const int bid = blockIdx.x, tid = threadIdx.x;
    const int b = bid >> 7, y = bid & 127;
    for (int i = tid; i < 16384; i += 256) {
        int c = i >> 7, xc = i & 127;
        tile[c * 137 + xc] = f2b(xg[((b * 128 + c) * 128 + y) * 128 + xc]);
    }
    __syncthreads();
    for (int i = tid; i < 16384; i += 256) {
        int xc = i >> 7, c = i & 127;
        xt[((b * 128 + y) * 128 + xc) * 128 + c] = tile[c * 137 + xc];
    }
}

// ===================== FAST kernel (needs xt in ws) ======================
// WG = 1024 threads (16 waves), one (b, blk). x fragments read DIRECTLY from
// global xt (coalesced b128, L2-resident via XCD swizzle) -> no s_x in LDS.
// LDS (u16): t_sw[64][136] @0 (o_sw[64][72] overlays it after S is done)
//            v_sw[64][232] @8704 | p_sw[64][232] @23552
//            vmul[224] f32 @ byte 76800.  Total 77696 B -> 2 WG/CU (32 waves).
// Softmax denominators via accs = MFMA(pa, ones) in PV (R6-proven): row-sums
// land per-lane in C/D layout exactly where the divide needs them; the
// shuffle-reduce and s_part are gone. 4 barriers/head (new B4 after E since
// o overlays t). Plain launch_bounds(1024): allocator's 64-VGPR target now
// matches the real 8-waves/EU occupancy -> no spill (R0-family live set).
__global__ __launch_bounds__(1024)
void halo_attn_fast(const u16* __restrict__ xt,
                    const u16* __restrict__ wqk,
                    const u16* __restrict__ wvt,
                    const u16* __restrict__ wot,
                    const float* __restrict__ bo,
                    float* __restrict__ outg)
{
    extern __shared__ u16 lds[];
    u16* t_sw = lds;           // also o_sw after PV
    u16* v_sw = lds + 8704;
    u16* p_sw = lds + 23552;
    float* vmul = (float*)((char*)lds + 76800);

    const int tid  = threadIdx.x;
    const int w    = tid >> 6;
    const int m    = tid & 15;
    const int quad = (tid & 63) >> 4;

    // XCD-swizzle: 128 consecutive logical blocks per XCD (window L2 reuse)
    const int wg = (blockIdx.x >> 3) + (blockIdx.x & 7) * 128;
    const int b   = wg >> 8;
    const int blk = wg & 255;
    const int by = blk >> 4, bx = blk & 15;
    const int y0 = by * 8 - 3, x0 = bx * 8 - 3;
    const bool inb = (by >= 1) && (by <= 14) && (bx >= 1) && (bx <= 14);

    const short8 zero8 = {0, 0, 0, 0, 0, 0, 0, 0};

    // ---- zero v/p pad chunks 26..28 (j = 208..231) ----
    for (int t = tid; t < 384; t += 1024) {
        int half2 = t / 192, u2 = t - half2 * 192;
        int r = u2 / 3, ch = 26 + (u2 - r * 3);
        u16* base = half2 ? p_sw : v_sw;
        *(short8*)(base + r * 232 + ch * 8) = zero8;
    }
    // ---- validity mask table ----
    if (tid < 224) {
        int j = tid;
        float v = 0.f;
        if (j < 196) {
            int wy = j / 14, wx = j - wy * 14;
            if (inb || (((unsigned)(y0 + wy) < 128u) && ((unsigned)(x0 + wx) < 128u)))
                v = 1.f;
        }
        vmul[j] = v;
    }

    // ---- wave roles (fixed) ----
    int nt = 0, sub = 0, startjt = 0, cnt = 0;
    if (w >= 4) {
        int u = w - 4;
        nt = u & 3;              // V: dv-tile;  S: it (same index)
        sub = u >> 2;            // jt group {0-4 | 5-8 | 9-12}
        startjt = sub ? (1 + 4 * sub) : 0;
        cnt = sub ? 4 : 5;
    }

    // ---- per-lane row offsets into xt (u16 elements), clamped ----
    unsigned rowoff[5];
    if (w < 4) {
#pragma unroll
        for (int it = 0; it < 4; ++it) {
            int i = it * 16 + m;                      // interior: always in-bounds
            rowoff[it] = (unsigned)(((b * 128 + by * 8 + (i >> 3)) * 128 +
                                     bx * 8 + (i & 7)) * 128);
        }
        rowoff[4] = 0;
    } else {
#pragma unroll
        for (int jj = 0; jj < 5; ++jj) {
            int jt = startjt + jj;
            int j = jt * 16 + m;                      // <= 223
            int wy = j / 14, wx = j - wy * 14;
            int gy = y0 + wy, gx = x0 + wx;
            gy = gy < 0 ? 0 : (gy > 127 ? 127 : gy);  // masked rows: any finite data
            gx = gx < 0 ? 0 : (gx > 127 ? 127 : gx);
            rowoff[jj] = (unsigned)(((b * 128 + gy) * 128 + gx) * 128);
        }
    }

    const short os1 = (short)0x3F80;                  // bf16 1.0
    const short8 ones8 = {os1, os1, os1, os1, os1, os1, os1, os1};

    float4v res[2];
    res[0] = (float4v){0.f, 0.f, 0.f, 0.f};
    res[1] = (float4v){0.f, 0.f, 0.f, 0.f};

#pragma unroll 1
    for (int h = 0; h < 8; ++h) {
        // ===== Phase T (waves 0..3) + V (waves 4..15) =====
        if (w < 4) {
#pragma unroll
            for (int p2 = 0; p2 < 2; ++p2) {
                short8 bq[4];
#pragma unroll
                for (int kk = 0; kk < 4; ++kk)
                    bq[kk] = *(const short8*)(wqk + h * 16384 +
                                 ((2 * w + p2) * 16 + m) * 128 + kk * 32 + quad * 8);
#pragma unroll 1
                for (int it = 0; it < 4; ++it) {
                    float4v c = {0.f, 0.f, 0.f, 0.f};
#pragma unroll
                    for (int kk = 0; kk < 4; ++kk) {
                        short8 a = *(const short8*)(xt + rowoff[it] +
                                                    kk * 32 + quad * 8);
                        c = MFMA(a, bq[kk], c);
                    }
#pragma unroll
                    for (int r = 0; r < 4; ++r)
                        t_sw[(it * 16 + quad * 4 + r) * 136 + (2 * w + p2) * 16 + m]
                            = f2b(c[r]);
                }
            }
        } else {
            short8 bv[4];
#pragma unroll
            for (int kk = 0; kk < 4; ++kk)
                bv[kk] = *(const short8*)(wvt + h * 8192 + (nt * 16 + m) * 128 +
                                          kk * 32 + quad * 8);
#pragma unroll 1
            for (int jj = 0; jj < 5; ++jj) if (jj < cnt) {
                int jt = startjt + jj;
                float4v c = {0.f, 0.f, 0.f, 0.f};
#pragma unroll
                for (int kk = 0; kk < 4; ++kk) {
                    short8 a = *(const short8*)(xt + rowoff[jj] + kk * 32 + quad * 8);
                    c = MFMA(a, bv[kk], c);
                }
                short4v pk;
#pragma unroll
                for (int r = 0; r < 4; ++r) pk[r] = (short)f2b(c[r]);
                *(short4v*)(v_sw + (nt * 16 + m) * 232 + jt * 16 + quad * 4) = pk;
            }
        }
        __syncthreads();   // B1: t, v ready

        // ===== Phase S (waves 4..15): sim = t @ x_win^T, exp, write p =====
        if (w >= 4) {
            const int it = nt;
            short8 ta[4];
#pragma unroll
            for (int kk = 0; kk < 4; ++kk)
                ta[kk] = *(const short8*)(t_sw + (it * 16 + m) * 136 +
                                          kk * 32 + quad * 8);
#pragma unroll 1
            for (int jj = 0; jj < 5; ++jj) if (jj < cnt) {
                int jt = startjt + jj;
                float4v c = {0.f, 0.f, 0.f, 0.f};
#pragma unroll
                for (int kk = 0; kk < 4; ++kk) {
                    short8 xb = *(const short8*)(xt + rowoff[jj] + kk * 32 + quad * 8);
                    c = MFMA(ta[kk], xb, c);
                }
                int j = jt * 16 + m;
                float vm = vmul[j];   // masked j: finite sim * 0 = 0
#pragma unroll
                for (int r = 0; r < 4; ++r) {
                    float p = __expf(c[r]) * vm;
                    p_sw[(it * 16 + quad * 4 + r) * 232 + j] = f2b(p);
                }
            }
        }
        __syncthreads();   // B2: p ready

        // ===== Phase PV (all 16): o = p @ v^T; denom via MFMA(pa, ones) =====
        {
            const int it = w & 3, nt2 = w >> 2;
            float4v c = {0.f, 0.f, 0.f, 0.f};
            float4v cs = {0.f, 0.f, 0.f, 0.f};
#pragma unroll
            for (int kk = 0; kk < 7; ++kk) {
                short8 pa = *(const short8*)(p_sw + (it * 16 + m) * 232 +
                                             kk * 32 + quad * 8);
                short8 vb = *(const short8*)(v_sw + (nt2 * 16 + m) * 232 +
                                             kk * 32 + quad * 8);
                c  = MFMA(pa, vb, c);
                cs = MFMA(pa, ones8, cs);   // row-sums, same C/D layout as c
            }
#pragma unroll
            for (int r = 0; r < 4; ++r) {
                int i = it * 16 + quad * 4 + r;
                t_sw[i * 72 + nt2 * 16 + m] = f2b(c[r] / cs[r]);  // o overlays t
            }
        }
        __syncthreads();   // B3: o ready

        // ===== Phase E (all 16): res += o @ Wo_h =====
        {
            const int ct = w & 7, itp = w >> 3;
            short8 bw[2];
#pragma unroll
            for (int kk = 0; kk < 2; ++kk)
                bw[kk] = *(const short8*)(wot + (ct * 16 + m) * 512 + h * 64 +
                                          kk * 32 + quad * 8);
#pragma unroll
            for (int t2 = 0; t2 < 2; ++t2) {
                int it = itp * 2 + t2;
                float4v c = res[t2];
#pragma unroll
                for (int kk = 0; kk < 2; ++kk) {
                    short8 ao = *(const short8*)(t_sw + (it * 16 + m) * 72 +
                                                 kk * 32 + quad * 8);
                    c = MFMA(ao, bw[kk], c);
                }
                res[t2] = c;
            }
        }
        __syncthreads();   // B4: o (in t region) fully read before next T writes
    } // heads

    // ---- store fp32 out[b][ch][gy][gx] ----
    {
        const int ct = w & 7, itp = w >> 3;
        const int ch = ct * 16 + m;
        const float bias = bo[ch];
#pragma unroll
        for (int t2 = 0; t2 < 2; ++t2) {
#pragma unroll
            for (int r = 0; r < 4; ++r) {
                int i = (itp * 2 + t2) * 16 + quad * 4 + r;
                int gy = by * 8 + (i >> 3), gx = bx * 8 + (i & 7);
                outg[((b * 128 + ch) * 128 + gy) * 128 + gx] = res[t2][r] + bias;
            }
        }
    }
}

// ===================== SAFE kernel (verbatim round-0, 374us) =====================
__global__ __launch_bounds__(1024)
void halo_attn_safe(const float* __restrict__ xg,
                    const u16* __restrict__ wqk,
                    const u16* __restrict__ wvt,
                    const u16* __restrict__ wot,
                    const float* __restrict__ bo,
                    float* __restrict__ outg)
{
    extern __shared__ u16 lds[];
    u16* s_x  = lds;
    u16* t_sw = lds + 28288;
    u16* v_sw = lds + 36992;
    u16* p_sw = lds + 51840;
    u16* o_sw = lds + 66688;
    float* s_part = (float*)((char*)lds + 142592);

    const int tid  = threadIdx.x;
    const int w    = tid >> 6;
    const int lane = tid & 63;
    const int m    = lane & 15;
    const int quad = lane >> 4;

    const int wg = (blockIdx.x >> 3) + (blockIdx.x & 7) * 128;
    const int b   = wg >> 8;
    const int blk = wg & 255;
    const int by = blk >> 4, bx = blk & 15;
    const int y0 = by * 8 - 3, x0 = bx * 8 - 3;

    const short8 zero8 = {0, 0, 0, 0, 0, 0, 0, 0};

    for (int job = tid; job < 208 * 16; job += 1024) {
        int row = job >> 4, cc = job & 15;
        short8 pk = zero8;
        if (row < 196) {
            int wy = row / 14, wx = row - wy * 14;
            int gy = y0 + wy, gx = x0 + wx;
            if ((unsigned)gy < 128u && (unsigned)gx < 128u) {
                const float* xp = xg + ((b * 128 + cc * 8) * 128 + gy) * 128 + gx;
#pragma unroll
                for (int r = 0; r < 8; ++r)
                    pk[r] = (short)f2b(xp[r * 16384]);
            }
        }
        *(short8*)(s_x + row * 136 + cc * 8) = pk;
    }
    for (int t = tid; t < 384; t += 1024) {
        int half = t / 192, u = t - half * 192;
        int r = u / 3, ch = 26 + (u - r * 3);
        u16* base = half ? p_sw : v_sw;
        *(short8*)(base + r * 232 + ch * 8) = zero8;
    }
    __syncthreads();

    float4v res[2];
    res[0] = (float4v){0.f, 0.f, 0.f, 0.f};
    res[1] = (float4v){0.f, 0.f, 0.f, 0.f};

    for (int h = 0; h < 8; ++h) {
        if (w < 4) {
            short8 bq[2][4];
#pragma unroll
            for (int p2 = 0; p2 < 2; ++p2)
#pragma unroll
                for (int kk = 0; kk < 4; ++kk)
                    bq[p2][kk] = *(const short8*)(wqk + h * 16384 +
                                 ((2 * w + p2) * 16 + m) * 128 + kk * 32 + quad * 8);
#pragma unroll 1
            for (int it = 0; it < 4; ++it) {
                int i = it * 16 + m;
                int jq = ((i >> 3) + 3) * 14 + (i & 7) + 3;
                short8 xa[4];
#pragma unroll
                for (int kk = 0; kk < 4; ++kk)
                    xa[kk] = *(const short8*)(s_x + jq * 136 + kk * 32 + quad * 8);
#pragma unroll
                for (int p2 = 0; p2 < 2; ++p2) {
                    float4v c = {0.f, 0.f, 0.f, 0.f};
#pragma unroll
                    for (int kk = 0; kk < 4; ++kk) c = MFMA(xa[kk], bq[p2][kk], c);
#pragma unroll
                    for (int r = 0; r < 4; ++r)
                        t_sw[(it * 16 + quad * 4 + r) * 136 + (2 * w + p2) * 16 + m]
                            = f2b(c[r]);
                }
            }
        } else {
            const int u = w - 4;
            const int nt = u & 3, sub = u >> 2;
            const int start = sub ? (1 + 4 * sub) : 0;
            const int count = sub ? 4 : 5;
            short8 bv[4];
#pragma unroll
            for (int kk = 0; kk < 4; ++kk)
                bv[kk] = *(const short8*)(wvt + h * 8192 + (nt * 16 + m) * 128 +
                                          kk * 32 + quad * 8);
#pragma unroll 1
            for (int jj = 0; jj < count; ++jj) {
                int jt = start + jj;
                float4v c = {0.f, 0.f, 0.f, 0.f};
#pragma unroll
                for (int kk = 0; kk < 4; ++kk) {
                    short8 xa = *(const short8*)(s_x + (jt * 16 + m) * 136 +
                                                 kk * 32 + quad * 8);
                    c = MFMA(xa, bv[kk], c);
                }
                short4v pk;
#pragma unroll
                for (int r = 0; r < 4; ++r) pk[r] = (short)f2b(c[r]);
                *(short4v*)(v_sw + (nt * 16 + m) * 232 + jt * 16 + quad * 4) = pk;
            }
        }
        __syncthreads();

        {
            const int it = w & 3, q4 = w >> 2;
            const int start = q4 ? (1 + 3 * q4) : 0;
            const int count = q4 ? 3 : 4;
            short8 ta[4];
#pragma unroll
            for (int kk = 0; kk < 4; ++kk)
                ta[kk] = *(const short8*)(t_sw + (it * 16 + m) * 136 +
                                          kk * 32 + quad * 8);
            float lsum[4] = {0.f, 0.f, 0.f, 0.f};
#pragma unroll 1
            for (int jj = 0; jj < count; ++jj) {
                int jt = start + jj;
                float4v c = {0.f, 0.f, 0.f, 0.f};
#pragma unroll
                for (int kk = 0; kk < 4; ++kk) {
                    short8 xb = *(const short8*)(s_x + (jt * 16 + m) * 136 +
                                                 kk * 32 + quad * 8);
                    c = MFMA(ta[kk], xb, c);
                }
                int j = jt * 16 + m;
                int wy = j / 14, wx = j - wy * 14;
                bool ok = (j < 196) && ((unsigned)(y0 + wy) < 128u) &&
                          ((unsigned)(x0 + wx) < 128u);
#pragma unroll
                for (int r = 0; r < 4; ++r) {
                    float p = ok ? __expf(c[r]) : 0.f;
                    lsum[r] += p;
                    p_sw[(it * 16 + quad * 4 + r) * 232 + j] = f2b(p);
                }
            }
#pragma unroll
            for (int mk = 1; mk < 16; mk <<= 1)
#pragma unroll
                for (int r = 0; r < 4; ++r)
                    lsum[r] += __shfl_xor(lsum[r], mk, 64);
            if (m == 0) {
#pragma unroll
                for (int r = 0; r < 4; ++r)
                    s_part[q4 * 64 + it * 16 + quad * 4 + r] = lsum[r];
            }
        }
        __syncthreads();

        {
            const int it = w & 3, nt2 = w >> 2;
            float4v c = {0.f, 0.f, 0.f, 0.f};
#pragma unroll
            for (int kk = 0; kk < 7; ++kk) {
                short8 pa = *(const short8*)(p_sw + (it * 16 + m) * 232 +
                                             kk * 32 + quad * 8);
                short8 vb = *(const short8*)(v_sw + (nt2 * 16 + m) * 232 +
                                             kk * 32 + quad * 8);
                c = MFMA(pa, vb, c);
            }
#pragma unroll
            for (int r = 0; r < 4; ++r) {
                int i = it * 16 + quad * 4 + r;
                float ss = s_part[i] + s_part[64 + i] + s_part[128 + i] + s_part[192 + i];
                o_sw[i * 72 + nt2 * 16 + m] = f2b(c[r] / ss);
            }
        }
        __syncthreads();

        {
            const int ct = w & 7, itp = w >> 3;
            short8 bw[2];
#pragma unroll
            for (int kk = 0; kk < 2; ++kk)
                bw[kk] = *(const short8*)(wot + (ct * 16 + m) * 512 + h * 64 +
                                          kk * 32 + quad * 8);
#pragma unroll
            for (int t2 = 0; t2 < 2; ++t2) {
                int it = itp * 2 + t2;
                float4v c = res[t2];
#pragma unroll
                for (int kk = 0; kk < 2; ++kk) {
                    short8 ao = *(const short8*)(o_sw + (it * 16 + m) * 72 +
                                                 kk * 32 + quad * 8);
                    c = MFMA(ao, bw[kk], c);
                }
                res[t2] = c;
            }
        }
    } // heads

    {
        const int ct = w & 7, itp = w >> 3;
        const int ch = ct * 16 + m;
        const float bias = bo[ch];
#pragma unroll
        for (int t2 = 0; t2 < 2; ++t2) {
#pragma unroll
            for (int r = 0; r < 4; ++r) {
                int i = (itp * 2 + t2) * 16 + quad * 4 + r;
                int gy = by * 8 + (i >> 3), gx = bx * 8 + (i & 7);
                outg[((b * 128 + ch) * 128 + gy) * 128 + gx] = res[t2][r] + bias;
            }
        }
    }
}

extern "C" void kernel_launch(void* const* d_in, const int* in_sizes, int n_in,
                              void* d_out, int out_size, void* d_ws, size_t ws_size,
                              hipStream_t stream) {
    const float* x   = (const float*)d_in[0];
    const float* Wq  = (const float*)d_in[1];
    const float* Wkv = (const float*)d_in[2];
    const float* Wo  = (const float*)d_in[3];
    const float* bo  = (const float*)d_in[4];
    float* out = (float*)d_out;
    u16* ws = (u16*)d_ws;

    prep_weights<<<dim3(640), dim3(256), 0, stream>>>(Wq, Wkv, Wo, ws);

    const size_t need = 524288ull + 4ull * 128 * 128 * 128 * 2;  // 512KB + xt 16MB
    if (ws_size >= need) {
        u16* xt = ws + 262144;
        xt_prep<<<dim3(512), dim3(256), 0, stream>>>(x, xt);
        (void)hipFuncSetAttribute((const void*)halo_attn_fast,
                                  hipFuncAttributeMaxDynamicSharedMemorySize, 77696);
        halo_attn_fast<<<dim3(1024), dim3(1024), 77696, stream>>>(
            xt, ws, ws + 131072, ws + 196608, bo, out);
    } else {
        (void)hipFuncSetAttribute((const void*)halo_attn_safe,
                                  hipFuncAttributeMaxDynamicSharedMemorySize, 143616);
        halo_attn_safe<<<dim3(1024), dim3(1024), 143616, stream>>>(
            x, ws, ws + 131072, ws + 196608, bo, out);
    }
}